// Round 1
// 339.500 us; speedup vs baseline: 1.0092x; 1.0092x over previous
//
#include <hip/hip_runtime.h>
#include <math.h>

#define NB 96
#define NB2 (NB * NB)
#define DFEAT 64
#define NCLS 21
#define MARGIN 0.3

typedef int i4 __attribute__((ext_vector_type(4)));  // native vec for nontemporal builtin

// ---------------------------------------------------------------------------
// Single fused kernel. One block per (i,j) pair, 384 threads (6 waves).
//
// Phase 1: block recomputes row i of the pair data entirely on-chip
//   (4 threads per n; inputs are L2/L1-hot: logits row = 256B, feat2 = 24KB,
//   labels = 8KB shared by all 9216 blocks). ~12k double-FMAs per block,
//   hidden under the store stream of other resident blocks.
//     smat[n]   = share(i,n) ? +inf : mat[i,n]   (masked negative cosine)
//     sthr[n]   = MARGIN + mat[i,n]
//     svalid[n] = share(i,n) && n != i           (sames with diag removed)
//
// Phase 2: thread owns a fixed n-chunk q (24 chunks of 4 ints per k-row).
//   smat[4q..4q+3] cached in registers ONCE (4 ds_read_b64 total vs 36 in
//   the previous kernel); k-loop reads only sthr[k] (broadcast within each
//   24-lane k-group -> conflict-free). 6 nontemporal int4 stores per thread.
//   valid[i,j,k,n] = sames[i,j] & sames[i,k] & (j<k) & diffs[i,n]
//                    & (mat[i,n] <= MARGIN + max(mat[i,j], mat[i,k]))
// ---------------------------------------------------------------------------
__global__ __launch_bounds__(384) void fused_quad_kernel(
    const float* __restrict__ logits,
    const float* __restrict__ labels,
    const float* __restrict__ feat2,
    int* __restrict__ out) {
  const int bid = blockIdx.x;
  const int i = bid / NB;
  const int j = bid - i * NB;
  const int tid = threadIdx.x;

  __shared__ double smat[NB];          // diffs[i,n] ? mat[i,n] : +inf
  __shared__ double sthr[NB];          // MARGIN + mat[i,n]
  __shared__ unsigned char svalid[NB]; // sames[i,n]

  // ---- phase 1: row i of mat/thr/share, 4 threads per n --------------------
  {
    const int n = tid >> 2;   // 0..95
    const int l4 = tid & 3;   // 0..3 (aligned quad within a wave)
    const float* xi = logits + i * DFEAT + l4 * 16;
    const float* yn = feat2 + n * DFEAT + l4 * 16;
    double dot = 0.0, nx = 0.0, ny = 0.0;
#pragma unroll
    for (int d = 0; d < 16; ++d) {
      double a = (double)xi[d];
      double b = (double)yn[d];
      dot += a * b;
      nx += a * a;
      ny += b * b;
    }
    // reduce across the 4-lane group (aligned, within one wave)
    dot += __shfl_xor(dot, 1); nx += __shfl_xor(nx, 1); ny += __shfl_xor(ny, 1);
    dot += __shfl_xor(dot, 2); nx += __shfl_xor(nx, 2); ny += __shfl_xor(ny, 2);
    if (l4 == 0) {
      nx = fmax(sqrt(nx), 1e-12);
      ny = fmax(sqrt(ny), 1e-12);
      double m = -(dot / (nx * ny));
      // share(i,n): labels are exact 0.0/1.0 so the f32 dot is an exact count
      const float* li = labels + i * NCLS;
      const float* ln = labels + n * NCLS;
      float ld = 0.f;
#pragma unroll
      for (int c = 0; c < NCLS; ++c) ld += li[c] * ln[c];
      const bool share = (ld > 0.f);
      smat[n] = share ? 1e300 : m;  // diagonal NOT excluded from diffs (ref)
      sthr[n] = MARGIN + m;
      svalid[n] = (share && n != i) ? 1 : 0;
    }
  }
  __syncthreads();

  // ---- phase 2: stream the 96x96 (k,n) slab --------------------------------
  const bool sames_ij = (svalid[j] != 0);
  const double thr_ij = sthr[j];
  i4* outp = (i4*)(out + (size_t)bid * (size_t)NB2);

  const int q = tid % 24;   // n-chunk index, fixed per thread
  const int kg = tid / 24;  // 0..15, each owns 6 k-rows
  const int n0 = q * 4;
  const double d0 = smat[n0 + 0];
  const double d1 = smat[n0 + 1];
  const double d2 = smat[n0 + 2];
  const double d3 = smat[n0 + 3];

#pragma unroll
  for (int r = 0; r < 6; ++r) {
    const int k = kg * 6 + r;
    i4 v = (i4)(0);
    if (sames_ij && svalid[k] && (j < k)) {
      const double t = fmax(thr_ij, sthr[k]);
      v.x = (d0 <= t) ? 1 : 0;
      v.y = (d1 <= t) ? 1 : 0;
      v.z = (d2 <= t) ? 1 : 0;
      v.w = (d3 <= t) ? 1 : 0;
    }
    __builtin_nontemporal_store(v, &outp[k * 24 + q]);
  }
}

extern "C" void kernel_launch(void* const* d_in, const int* in_sizes, int n_in,
                              void* d_out, int out_size, void* d_ws, size_t ws_size,
                              hipStream_t stream) {
  const float* logits = (const float*)d_in[0];  // [96,64]
  const float* labels = (const float*)d_in[1];  // [96,21]
  const float* feat2  = (const float*)d_in[2];  // [96,64]
  int* out = (int*)d_out;                       // [96,96,96,96] as 0/1 int32

  fused_quad_kernel<<<NB2, 384, 0, stream>>>(logits, labels, feat2, out);
}

// Round 2
// 339.202 us; speedup vs baseline: 1.0100x; 1.0009x over previous
//
#include <hip/hip_runtime.h>
#include <math.h>

#define NB 96
#define NB2 (NB * NB)
#define DFEAT 64
#define NCLS 21
#define MARGIN 0.3

typedef int i4 __attribute__((ext_vector_type(4)));

// ---------------------------------------------------------------------------
// Single fused kernel. One block per (i,j) pair, 384 threads (6 waves).
//
// valid[i,j,k,n] = sames[i,j] & sames[i,k] & (j<k) & diffs[i,n]
//                  & (mat[i,n] <= MARGIN + max(mat[i,j], mat[i,k]))
//
// Prologue (NEW): rows k <= j are zero regardless of any data (j<k required),
//   so they are stored before phase 1 with zero dependencies -- the write
//   pipe is busy while phase-1 loads and f64 math are still in flight.
//   This is 50% of all output bytes on average.
// Phase 1: block recomputes row i of mat/thr/share on-chip (inputs L2-hot,
//   4 threads per n, f64 to match the f64-reference booleans exactly).
// Epilogue: rows k > j; thread owns fixed n-chunk q, k steps by 16.
//   smat[4q..4q+3] cached in registers once; sthr[k] is a group-broadcast
//   LDS read. Plain (temporal) stores this round: rule out nt sub-line
//   write amplification; full lines are covered so L2 writeback runs at
//   fill-kernel rates.
// ---------------------------------------------------------------------------
__global__ __launch_bounds__(384) void fused_quad_kernel(
    const float* __restrict__ logits,
    const float* __restrict__ labels,
    const float* __restrict__ feat2,
    int* __restrict__ out) {
  const int bid = blockIdx.x;
  const int i = bid / NB;
  const int j = bid - i * NB;
  const int tid = threadIdx.x;
  const int q = tid % 24;   // n-chunk index (0..23), fixed per thread
  const int kr = tid / 24;  // k-row residue (0..15)

  i4* outp = (i4*)(out + (size_t)bid * (size_t)NB2);

  // ---- prologue: rows k in [0, j] are unconditionally zero -----------------
  {
    const i4 z = {0, 0, 0, 0};
    for (int k = kr; k <= j; k += 16)
      outp[k * 24 + q] = z;
  }

  __shared__ double smat[NB];          // diffs[i,n] ? mat[i,n] : +inf
  __shared__ double sthr[NB];          // MARGIN + mat[i,n]
  __shared__ unsigned char svalid[NB]; // sames[i,n]

  // ---- phase 1: row i of mat/thr/share, 4 threads per n --------------------
  {
    const int n = tid >> 2;   // 0..95
    const int l4 = tid & 3;   // 0..3 (aligned quad within a wave)
    const float* xi = logits + i * DFEAT + l4 * 16;
    const float* yn = feat2 + n * DFEAT + l4 * 16;
    double dot = 0.0, nx = 0.0, ny = 0.0;
#pragma unroll
    for (int d = 0; d < 16; ++d) {
      double a = (double)xi[d];
      double b = (double)yn[d];
      dot += a * b;
      nx += a * a;
      ny += b * b;
    }
    dot += __shfl_xor(dot, 1); nx += __shfl_xor(nx, 1); ny += __shfl_xor(ny, 1);
    dot += __shfl_xor(dot, 2); nx += __shfl_xor(nx, 2); ny += __shfl_xor(ny, 2);
    if (l4 == 0) {
      nx = fmax(sqrt(nx), 1e-12);
      ny = fmax(sqrt(ny), 1e-12);
      double m = -(dot / (nx * ny));
      // labels are exact 0.0/1.0 so the f32 dot is an exact count
      const float* li = labels + i * NCLS;
      const float* ln = labels + n * NCLS;
      float ld = 0.f;
#pragma unroll
      for (int c = 0; c < NCLS; ++c) ld += li[c] * ln[c];
      const bool share = (ld > 0.f);
      smat[n] = share ? 1e300 : m;  // diagonal NOT excluded from diffs (ref)
      sthr[n] = MARGIN + m;
      svalid[n] = (share && n != i) ? 1 : 0;
    }
  }
  __syncthreads();

  // ---- epilogue: rows k in (j, 96) -----------------------------------------
  const bool sames_ij = (svalid[j] != 0);
  const double thr_ij = sthr[j];
  const int n0 = q * 4;
  const double d0 = smat[n0 + 0];
  const double d1 = smat[n0 + 1];
  const double d2 = smat[n0 + 2];
  const double d3 = smat[n0 + 3];

  for (int k = j + 1 + kr; k < NB; k += 16) {
    i4 v = {0, 0, 0, 0};
    if (sames_ij && svalid[k]) {
      const double t = fmax(thr_ij, sthr[k]);
      v.x = (d0 <= t) ? 1 : 0;
      v.y = (d1 <= t) ? 1 : 0;
      v.z = (d2 <= t) ? 1 : 0;
      v.w = (d3 <= t) ? 1 : 0;
    }
    outp[k * 24 + q] = v;
  }
}

extern "C" void kernel_launch(void* const* d_in, const int* in_sizes, int n_in,
                              void* d_out, int out_size, void* d_ws, size_t ws_size,
                              hipStream_t stream) {
  const float* logits = (const float*)d_in[0];  // [96,64]
  const float* labels = (const float*)d_in[1];  // [96,21]
  const float* feat2  = (const float*)d_in[2];  // [96,64]
  int* out = (int*)d_out;                       // [96,96,96,96] as 0/1 int32

  fused_quad_kernel<<<NB2, 384, 0, stream>>>(logits, labels, feat2, out);
}